// Round 6
// baseline (46.735 us; speedup 1.0000x reference)
//
#include <hip/hip_runtime.h>

#define F_IN    32768
#define HID     64
#define NB_OBJ  16
#define BATCH   64
#define N_AGENTS 4
#define N_ACT   13
#define NEG_SLOPE 0.01f

#define FC      64               // f-chunk width per K2 block
#define NCHUNK  (F_IN / FC)      // 512 split-K chunks

typedef float f32x4 __attribute__((ext_vector_type(4)));

// static scratch:
// g_s    [BATCH][F_IN]          = 8 MiB   (node-mean, already /16)
// g_part [NCHUNK][BATCH][HID]   = 8 MiB   (split-K partials)
__device__ float g_s[BATCH * F_IN];
__device__ float g_part[NCHUNK * BATCH * HID];

// ---------------------------------------------------------------------------
// K1: pure streaming node-mean. s[b][f] = (1/16) * sum_o u[b][o][f].
// grid = 2048, block = 256. Each thread: 16 independent float4 loads, 1 store.
// Perfect coalescing: 1 KiB per wave-instruction. No LDS, no barriers.
// ---------------------------------------------------------------------------
__global__ __launch_bounds__(256, 4)
void k_mean(const float* __restrict__ u) {
    const int t   = threadIdx.x;
    const int bid = blockIdx.x;
    const int b   = bid >> 5;                       // 32 blocks per batch
    const int fq  = (bid & 31) * 256 + t;           // float4 index in row, 0..8191
    const float* base = u + (size_t)b * (NB_OBJ * F_IN) + (size_t)fq * 4;

    f32x4 a0 = (f32x4)(0.f), a1 = (f32x4)(0.f);
    #pragma unroll
    for (int o = 0; o < NB_OBJ; o += 2) {
        a0 += *reinterpret_cast<const f32x4*>(base + (size_t)o * F_IN);
        a1 += *reinterpret_cast<const f32x4*>(base + (size_t)(o + 1) * F_IN);
    }
    f32x4 s = (a0 + a1) * (1.0f / (float)NB_OBJ);
    *reinterpret_cast<f32x4*>(g_s + (size_t)b * F_IN + (size_t)fq * 4) = s;
}

// ---------------------------------------------------------------------------
// K2: split-K GEMM chunk: part[blk][b][h] = sum_{f in chunk} s[b][f] w[f][h].
// grid = NCHUNK (512), block = 256 (4 waves). s/w are L2/L3-hot. LDS tile
// for s; w column slice in registers.
// ---------------------------------------------------------------------------
__global__ __launch_bounds__(256, 4)
void k_gemm(const float* __restrict__ w) {
    __shared__ float xbar[BATCH][FC + 4];   // row pitch 68 floats
    const int t    = threadIdx.x;
    const int blk  = blockIdx.x;
    const int f0   = blk * FC;
    const int lane = t & 63;
    const int wv   = t >> 6;                // 0..3

    // stage full 64x64 s tile: thread (b = t>>2, j = t&3) loads 4 float4s
    // at columns (j+4q)*4, q=0..3  -> 256 thr x 4 x 4 floats = 4096 floats.
    {
        const int b = t >> 2, j = t & 3;
        const float* sp = g_s + (size_t)b * F_IN + f0;
        #pragma unroll
        for (int q = 0; q < 4; ++q) {
            f32x4 v = *reinterpret_cast<const f32x4*>(sp + (j + 4 * q) * 4);
            *reinterpret_cast<f32x4*>(&xbar[b][(j + 4 * q) * 4]) = v;
        }
    }

    // w column slice: wreg[f] = w[(f0+f)*HID + lane]
    float wreg[FC];
    {
        const float* wp = w + (size_t)f0 * HID + lane;
        #pragma unroll
        for (int f = 0; f < FC; ++f) wreg[f] = wp[f * HID];
    }
    __syncthreads();

    // each wave computes 16 batches; lane = output h. xbar reads broadcast.
    {
        float* pout = g_part + (size_t)blk * (BATCH * HID) + lane;
        #pragma unroll
        for (int bb = 0; bb < 16; ++bb) {
            const int b = wv * 16 + bb;
            float acc = 0.f;
            #pragma unroll
            for (int fq = 0; fq < FC / 4; ++fq) {
                f32x4 xb = *reinterpret_cast<const f32x4*>(&xbar[b][fq * 4]);
                acc += xb.x * wreg[fq * 4 + 0];
                acc += xb.y * wreg[fq * 4 + 1];
                acc += xb.z * wreg[fq * 4 + 2];
                acc += xb.w * wreg[fq * 4 + 3];
            }
            pout[b * HID] = acc;
        }
    }
}

// ---------------------------------------------------------------------------
// K3: per-batch split-K reduction + heads + argmax gather.
// grid = BATCH (64), block = 512 (8 waves). Partials are L2/L3-resident.
// ---------------------------------------------------------------------------
__global__ __launch_bounds__(512)
void k_tail(const float* __restrict__ gcn_b,
            const float* __restrict__ w1, const float* __restrict__ b1,
            const float* __restrict__ w2, const float* __restrict__ b2,
            const float* __restrict__ actions, float* __restrict__ out) {
    const int b = blockIdx.x;
    const int t = threadIdx.x;
    __shared__ float red[8][HID];
    __shared__ float pooled[HID];
    __shared__ float zbuf[N_AGENTS][HID];
    __shared__ float qbuf[N_AGENTS][N_ACT];

    // phase 1: pooled[h] = sum_k part[k][b][h] + gcn_b[h]
    {
        const int h  = t & 63;
        const int kg = t >> 6;   // 0..7
        const float* p = g_part + (size_t)(kg * 64) * (BATCH * HID)
                       + (size_t)b * HID + h;
        float acc = 0.f;
        #pragma unroll 16
        for (int i = 0; i < 64; ++i)
            acc += p[(size_t)i * (BATCH * HID)];
        red[kg][h] = acc;
    }
    __syncthreads();
    if (t < HID) {
        float acc = gcn_b[t];
        #pragma unroll
        for (int kg = 0; kg < 8; ++kg) acc += red[kg][t];
        pooled[t] = acc;
    }
    __syncthreads();

    // phase 2: z[a][k] = leaky(b1 + sum_h pooled[h] * w1[a][h][k])
    if (t < N_AGENTS * HID) {
        const int a = t >> 6, k = t & 63;
        const float* w1p = w1 + a * (HID * HID) + k;
        float acc = b1[a * HID + k];
        #pragma unroll
        for (int hh = 0; hh < HID; ++hh) acc += pooled[hh] * w1p[hh * HID];
        zbuf[a][k] = (acc >= 0.f) ? acc : NEG_SLOPE * acc;
    }
    __syncthreads();

    // phase 3: q[a][c] = b2 + sum_h z[a][h] * w2[a][h][c]
    if (t < N_AGENTS * N_ACT) {
        const int a = t / N_ACT, c = t % N_ACT;
        const float* w2p = w2 + a * (HID * N_ACT) + c;
        float acc = b2[a * N_ACT + c];
        #pragma unroll
        for (int hh = 0; hh < HID; ++hh) acc += zbuf[a][hh] * w2p[hh * N_ACT];
        qbuf[a][c] = acc;
    }
    __syncthreads();

    // phase 4: argmax over actions (first-max, matching jnp.argmax), gather
    if (t < N_AGENTS) {
        const float* ap = actions + ((size_t)t * BATCH + b) * N_ACT;
        int best = 0; float bv = ap[0];
        for (int c = 1; c < N_ACT; ++c) {
            float v = ap[c];
            if (v > bv) { bv = v; best = c; }
        }
        out[t * BATCH + b] = qbuf[t][best];
    }
}

extern "C" void kernel_launch(void* const* d_in, const int* in_sizes, int n_in,
                              void* d_out, int out_size, void* d_ws, size_t ws_size,
                              hipStream_t stream) {
    const float* u   = (const float*)d_in[0];
    // d_in[1] = binary_tensor: dead in the reference computation
    const float* act = (const float*)d_in[2];
    const float* gw  = (const float*)d_in[3];
    const float* gb  = (const float*)d_in[4];
    const float* w1  = (const float*)d_in[5];
    const float* b1  = (const float*)d_in[6];
    const float* w2  = (const float*)d_in[7];
    const float* b2  = (const float*)d_in[8];
    float* out = (float*)d_out;

    hipLaunchKernelGGL(k_mean, dim3(2048),   dim3(256), 0, stream, u);
    hipLaunchKernelGGL(k_gemm, dim3(NCHUNK), dim3(256), 0, stream, gw);
    hipLaunchKernelGGL(k_tail, dim3(BATCH),  dim3(512), 0, stream,
                       gb, w1, b1, w2, b2, act, out);
}